// Round 1
// baseline (2241.195 us; speedup 1.0000x reference)
//
#include <hip/hip_runtime.h>
#include <hip/hip_bf16.h>
#include <math.h>

#define H_DIM 2880
#define F_DIM 2880
#define GU_DIM 5760
#define NE 16
#define NT 1024
#define TOPK 4

typedef float f32x4 __attribute__((ext_vector_type(4)));
typedef __bf16 bf16x8 __attribute__((ext_vector_type(8)));

__device__ __forceinline__ unsigned short f2bf(float f) {
    union { float f; unsigned u; } v; v.f = f;
    return (unsigned short)((v.u + 0x8000u) >> 16);   // round-half-up to bf16
}
__device__ __forceinline__ unsigned pk2(float a, float b) {
    return (unsigned)f2bf(a) | ((unsigned)f2bf(b) << 16);
}

// ---------------- router: logits -> top4 -> softmax -> counts ----------------
__global__ __launch_bounds__(64) void router_kernel(
    const float* __restrict__ x, const float* __restrict__ rw, const float* __restrict__ rb,
    int* counts, int* topk_idx, float* topk_score)
{
    int t = blockIdx.x, lane = threadIdx.x;
    const float* xr = x + (size_t)t * H_DIM;
    float acc[NE];
#pragma unroll
    for (int e = 0; e < NE; e++) acc[e] = 0.f;
    for (int h = lane; h < H_DIM; h += 64) {
        float xv = xr[h];
#pragma unroll
        for (int e = 0; e < NE; e++) acc[e] += xv * rw[e * H_DIM + h];
    }
    float lg[NE];
#pragma unroll
    for (int e = 0; e < NE; e++) {
        float v = acc[e];
#pragma unroll
        for (int off = 32; off > 0; off >>= 1) v += __shfl_down(v, off, 64);
        lg[e] = v;
    }
    if (lane == 0) {
#pragma unroll
        for (int e = 0; e < NE; e++) lg[e] += rb[e];
        int mask = 0; float tv[TOPK]; int ti[TOPK];
        for (int k = 0; k < TOPK; k++) {
            float best = -1e30f; int bi = 0;
            for (int e = 0; e < NE; e++)
                if (!((mask >> e) & 1) && lg[e] > best) { best = lg[e]; bi = e; }
            mask |= 1 << bi; tv[k] = best; ti[k] = bi;
        }
        float m = tv[0], s = 0.f, ex[TOPK];
        for (int k = 0; k < TOPK; k++) { ex[k] = expf(tv[k] - m); s += ex[k]; }
        float inv = 1.f / s;
        for (int k = 0; k < TOPK; k++) {
            topk_idx[t * TOPK + k] = ti[k];
            topk_score[t * TOPK + k] = ex[k] * inv;
            atomicAdd(&counts[ti[k]], 1);
        }
    }
}

__global__ void offsets_kernel(const int* counts, int* offsets) {
    if (threadIdx.x == 0 && blockIdx.x == 0) {
        int s = 0;
        for (int e = 0; e < NE; e++) { offsets[e] = s; s += counts[e]; }
        offsets[NE] = s;
    }
}

__global__ void scatter_kernel(const int* topk_idx, const float* topk_score,
                               const int* offsets, int* fills, int* entry, float* entry_score)
{
    int t = blockIdx.x * blockDim.x + threadIdx.x;
    if (t >= NT) return;
    for (int k = 0; k < TOPK; k++) {
        int e = topk_idx[t * TOPK + k];
        int pos = atomicAdd(&fills[e], 1);
        int i = offsets[e] + pos;
        entry[i] = t | (k << 16);
        entry_score[i] = topk_score[t * TOPK + k];
    }
}

// ---------------- GEMM1: act = GLU(x[tokens] @ gate_up_w[e] + b) ----------------
// tile 128x128, BK=32, 4 waves, each wave 64x64 via 4x4 of 16x16x32 bf16 MFMA
__global__ __launch_bounds__(256, 2) void gemm1_kernel(
    const float* __restrict__ x, const float* __restrict__ gw, const float* __restrict__ gb,
    const int* __restrict__ counts, const int* __restrict__ offsets,
    const int* __restrict__ entry, unsigned short* __restrict__ act)
{
    int e = blockIdx.z;
    int cnt = counts[e];
    int m0 = blockIdx.y * 128;
    if (m0 >= cnt) return;
    int n0 = blockIdx.x * 128;
    int off = offsets[e];

    __shared__ __align__(16) unsigned short As[128 * 40];  // [m][k] stride 40
    __shared__ __align__(16) unsigned short Bs[128 * 40];  // [n][k] stride 40, chunk-XOR swizzled
    __shared__ int toks[128];

    int tid = threadIdx.x;
    if (tid < 128) {
        int r = m0 + tid;
        toks[tid] = entry[off + (r < cnt ? r : 0)] & 0xFFFF;
    }
    __syncthreads();

    // A staging: 4 x float4 per thread (128 rows x 32 k fp32)
    int arow[4], akk[4]; const float* aptr[4];
#pragma unroll
    for (int i = 0; i < 4; i++) {
        int s = tid + i * 256;
        arow[i] = s >> 3; akk[i] = (s & 7) * 4;
        aptr[i] = x + (size_t)toks[arow[i]] * H_DIM + akk[i];
    }
    // B staging: thread owns 4k x 4n block
    int n4 = tid & 31, kb = tid >> 5;
    const float* bptr = gw + (size_t)e * H_DIM * GU_DIM + (size_t)kb * 4 * GU_DIM + n0 + n4 * 4;

    int wv = tid >> 6, lane = tid & 63;
    int wm = (wv & 1) * 64, wn = (wv >> 1) * 64;
    int r16 = lane & 15, q = lane >> 4;

    f32x4 acc[4][4] = {};
    int a_rd[4], b_rd[4];
#pragma unroll
    for (int i = 0; i < 4; i++) {
        int m = wm + i * 16 + r16;
        a_rd[i] = m * 40 + q * 8;
        int n = wn + i * 16 + r16;
        b_rd[i] = n * 40 + ((q ^ ((n >> 2) & 3)) * 8);
    }
    // B write addresses (4 per thread, one per local col)
    int bwr[4];
#pragma unroll
    for (int c = 0; c < 4; c++) {
        int nl = n4 * 4 + c;
        bwr[c] = nl * 40 + (((kb >> 1) ^ ((nl >> 2) & 3)) * 8) + (kb & 1) * 4;
    }

    for (int k0 = 0; k0 < H_DIM; k0 += 32) {
#pragma unroll
        for (int i = 0; i < 4; i++) {
            float4 v = *(const float4*)(aptr[i] + k0);
            *(uint2*)&As[arow[i] * 40 + akk[i]] = make_uint2(pk2(v.x, v.y), pk2(v.z, v.w));
        }
        float bvf[4][4];
#pragma unroll
        for (int j = 0; j < 4; j++) {
            float4 tv = *(const float4*)(bptr + (size_t)(k0 + j) * GU_DIM);
            bvf[j][0] = tv.x; bvf[j][1] = tv.y; bvf[j][2] = tv.z; bvf[j][3] = tv.w;
        }
#pragma unroll
        for (int c = 0; c < 4; c++)
            *(uint2*)&Bs[bwr[c]] = make_uint2(pk2(bvf[0][c], bvf[1][c]), pk2(bvf[2][c], bvf[3][c]));
        __syncthreads();

        bf16x8 af[4], bq[4];
#pragma unroll
        for (int i = 0; i < 4; i++) af[i] = *(const bf16x8*)&As[a_rd[i]];
#pragma unroll
        for (int i = 0; i < 4; i++) bq[i] = *(const bf16x8*)&Bs[b_rd[i]];
#pragma unroll
        for (int mi = 0; mi < 4; mi++)
#pragma unroll
            for (int ni = 0; ni < 4; ni++)
                acc[mi][ni] = __builtin_amdgcn_mfma_f32_16x16x32_bf16(af[mi], bq[ni], acc[mi][ni], 0, 0, 0);
        __syncthreads();
    }

    // epilogue: bias + GLU (gate=even col, up=odd col), store bf16 act
    const float* gbp = gb + (size_t)e * GU_DIM;
#pragma unroll
    for (int ni = 0; ni < 4; ni++) {
        int col = n0 + wn + ni * 16 + r16;
        float bias = gbp[col];
#pragma unroll
        for (int mi = 0; mi < 4; mi++) {
#pragma unroll
            for (int r = 0; r < 4; r++) {
                float v = acc[mi][ni][r] + bias;
                float vo = __shfl_xor(v, 1, 64);
                float gate = (lane & 1) ? vo : v;
                float up   = (lane & 1) ? v  : vo;
                gate = fminf(gate, 7.0f);
                up = fminf(fmaxf(up, -7.0f), 7.0f);
                float glu = gate / (1.0f + expf(-1.702f * gate));
                float a = (up + 1.0f) * glu;
                int row = m0 + wm + mi * 16 + q * 4 + r;
                if (row < cnt && !(lane & 1))
                    act[(size_t)(off + row) * F_DIM + (col >> 1)] = f2bf(a);
            }
        }
    }
}

// ---------------- GEMM2: out += score * (act @ down_w[e] + db) ----------------
__global__ __launch_bounds__(256, 2) void gemm2_kernel(
    const unsigned short* __restrict__ act, const float* __restrict__ dw, const float* __restrict__ db,
    const int* __restrict__ counts, const int* __restrict__ offsets,
    const int* __restrict__ entry, const float* __restrict__ entry_score,
    float* __restrict__ out)
{
    int e = blockIdx.z;
    int cnt = counts[e];
    int m0 = blockIdx.y * 128;
    if (m0 >= cnt) return;
    int n0 = blockIdx.x * 128;
    int off = offsets[e];

    __shared__ __align__(16) unsigned short As[128 * 40];
    __shared__ __align__(16) unsigned short Bs[128 * 40];
    __shared__ int tks[128];
    __shared__ float scs[128];

    int tid = threadIdx.x;
    if (tid < 128) {
        int r = m0 + tid;
        int idx = off + (r < cnt ? r : 0);
        tks[tid] = entry[idx];
        scs[tid] = entry_score[idx];
    }
    __syncthreads();

    // A staging: bf16 act, 2 x 16B per thread
    int arow[2], ak8[2]; const unsigned short* aptr[2];
#pragma unroll
    for (int i = 0; i < 2; i++) {
        int s = tid + i * 256;
        arow[i] = s >> 2; ak8[i] = (s & 3) * 8;
        aptr[i] = act + (size_t)(off + m0 + arow[i]) * F_DIM + ak8[i];
    }
    int n4 = tid & 31, kb = tid >> 5;
    int ncol = n0 + n4 * 4;
    bool nval = ncol < H_DIM;              // last n-tile is ragged (2880 % 128 = 64)
    const float* bptr = dw + (size_t)e * F_DIM * H_DIM + (size_t)kb * 4 * H_DIM + ncol;

    int wv = tid >> 6, lane = tid & 63;
    int wm = (wv & 1) * 64, wn = (wv >> 1) * 64;
    int r16 = lane & 15, q = lane >> 4;

    f32x4 acc[4][4] = {};
    int a_rd[4], b_rd[4];
#pragma unroll
    for (int i = 0; i < 4; i++) {
        int m = wm + i * 16 + r16;
        a_rd[i] = m * 40 + q * 8;
        int n = wn + i * 16 + r16;
        b_rd[i] = n * 40 + ((q ^ ((n >> 2) & 3)) * 8);
    }
    int bwr[4];
#pragma unroll
    for (int c = 0; c < 4; c++) {
        int nl = n4 * 4 + c;
        bwr[c] = nl * 40 + (((kb >> 1) ^ ((nl >> 2) & 3)) * 8) + (kb & 1) * 4;
    }

    for (int k0 = 0; k0 < F_DIM; k0 += 32) {
#pragma unroll
        for (int i = 0; i < 2; i++) {
            uint4 v = *(const uint4*)(aptr[i] + k0);
            *(uint4*)&As[arow[i] * 40 + ak8[i]] = v;
        }
        float bvf[4][4];
#pragma unroll
        for (int j = 0; j < 4; j++) {
            float4 tv = nval ? *(const float4*)(bptr + (size_t)(k0 + j) * H_DIM)
                             : make_float4(0.f, 0.f, 0.f, 0.f);
            bvf[j][0] = tv.x; bvf[j][1] = tv.y; bvf[j][2] = tv.z; bvf[j][3] = tv.w;
        }
#pragma unroll
        for (int c = 0; c < 4; c++)
            *(uint2*)&Bs[bwr[c]] = make_uint2(pk2(bvf[0][c], bvf[1][c]), pk2(bvf[2][c], bvf[3][c]));
        __syncthreads();

        bf16x8 af[4], bq[4];
#pragma unroll
        for (int i = 0; i < 4; i++) af[i] = *(const bf16x8*)&As[a_rd[i]];
#pragma unroll
        for (int i = 0; i < 4; i++) bq[i] = *(const bf16x8*)&Bs[b_rd[i]];
#pragma unroll
        for (int mi = 0; mi < 4; mi++)
#pragma unroll
            for (int ni = 0; ni < 4; ni++)
                acc[mi][ni] = __builtin_amdgcn_mfma_f32_16x16x32_bf16(af[mi], bq[ni], acc[mi][ni], 0, 0, 0);
        __syncthreads();
    }

    const float* dbp = db + (size_t)e * H_DIM;
#pragma unroll
    for (int ni = 0; ni < 4; ni++) {
        int col = n0 + wn + ni * 16 + r16;
        float bias = (col < H_DIM) ? dbp[col] : 0.f;
#pragma unroll
        for (int mi = 0; mi < 4; mi++) {
#pragma unroll
            for (int r = 0; r < 4; r++) {
                int lr = wm + mi * 16 + q * 4 + r;
                if (m0 + lr < cnt && col < H_DIM) {
                    int ev = tks[lr];
                    int tok = ev & 0xFFFF;
                    float v = (acc[mi][ni][r] + bias) * scs[lr];
                    atomicAdd(&out[(size_t)tok * H_DIM + col], v);
                }
            }
        }
    }
}

// ---------------- launch ----------------
extern "C" void kernel_launch(void* const* d_in, const int* in_sizes, int n_in,
                              void* d_out, int out_size, void* d_ws, size_t ws_size,
                              hipStream_t stream)
{
    const float* x  = (const float*)d_in[0];
    const float* rw = (const float*)d_in[1];
    const float* rb = (const float*)d_in[2];
    const float* gw = (const float*)d_in[3];
    const float* gb = (const float*)d_in[4];
    const float* dw = (const float*)d_in[5];
    const float* db = (const float*)d_in[6];
    float* out = (float*)d_out;

    char* ws = (char*)d_ws;
    int*   counts      = (int*)(ws);
    int*   fills       = (int*)(ws + 64);
    int*   offsets     = (int*)(ws + 128);
    int*   topk_idx    = (int*)(ws + 256);
    float* topk_score  = (float*)(ws + 16640);
    int*   entry       = (int*)(ws + 33024);
    float* entry_score = (float*)(ws + 49408);
    unsigned short* act = (unsigned short*)(ws + 131072);  // 4096 x 2880 bf16 = 23.6 MB

    hipMemsetAsync(ws, 0, 256, stream);                       // counts + fills
    hipMemsetAsync(d_out, 0, (size_t)out_size * 4, stream);   // accumulate target

    router_kernel<<<NT, 64, 0, stream>>>(x, rw, rb, counts, topk_idx, topk_score);
    offsets_kernel<<<1, 32, 0, stream>>>(counts, offsets);
    scatter_kernel<<<4, 256, 0, stream>>>(topk_idx, topk_score, offsets, fills, entry, entry_score);
    gemm1_kernel<<<dim3(45, 8, NE), 256, 0, stream>>>(x, gw, gb, counts, offsets, entry, act);
    gemm2_kernel<<<dim3(23, 8, NE), 256, 0, stream>>>(act, dw, db, counts, offsets, entry, entry_score, out);
}